// Round 2
// baseline (1262.701 us; speedup 1.0000x reference)
//
#include <hip/hip_runtime.h>
#include <hip/hip_cooperative_groups.h>
#include <math.h>

namespace cg = cooperative_groups;

// SGRUCell T=32 B=8 I=512 H=512, all f32.
// Persistent cooperative kernel: 256 blocks x 1024 threads, block k owns state
// rows (b, i) for i in {2k, 2k+1}, all b. dU/tE live in registers (8+8 per
// thread) across all 32 steps; te/h in LDS; weights staged once. One
// grid.sync() per step; h_t exchanged through o_outs (written anyway).

__device__ __forceinline__ float wred(float v) {
#pragma unroll
  for (int o = 32; o > 0; o >>= 1) v += __shfl_xor(v, o, 64);
  return v;
}
__device__ __forceinline__ float sigm(float x) { return 1.f / (1.f + __expf(-x)); }

__global__ void prenorm_kernel(const float* __restrict__ xv, const float* __restrict__ xg,
                               const float* __restrict__ hv, const float* __restrict__ hg,
                               float* __restrict__ scx, float* __restrict__ sch) {
  int r = blockIdx.x, L = threadIdx.x;
  const float* vrow; const float* g; float* o; int rr;
  if (r < 1536) { rr = r; vrow = xv + (size_t)r * 512; g = xg; o = scx; }
  else { rr = r - 1536; vrow = hv + (size_t)rr * 512; g = hg; o = sch; }
  float s = 0.f;
#pragma unroll
  for (int m = 0; m < 8; m++) { float v = vrow[m * 64 + L]; s = fmaf(v, v, s); }
  s = wred(s);
  if (L == 0) o[rr] = g[rr] / sqrtf(s);
}

__global__ __launch_bounds__(1024, 4) void persist_kernel(
    const float* __restrict__ x,
    const float* __restrict__ h0, const float* __restrict__ v0,
    const float* __restrict__ dU0, const float* __restrict__ te0,
    const float* __restrict__ tE0,
    const float* __restrict__ x2h_v, const float* __restrict__ x2h_b,
    const float* __restrict__ h2h_v, const float* __restrict__ h2h_b,
    const float* __restrict__ alpha,
    const float* __restrict__ h2mod_w, const float* __restrict__ h2mod_b,
    const float* __restrict__ modU_w, const float* __restrict__ modU_b,
    const float* __restrict__ scx, const float* __restrict__ sch,
    float* __restrict__ o_v, float* __restrict__ o_h,
    float* __restrict__ o_dU, float* __restrict__ o_te,
    float* __restrict__ o_tE, float* __restrict__ o_outs) {
  __shared__ float sh_h[4096];            // current h_t (and h_{t-1} before reload)
  __shared__ float sh_te[4096];           // eligibility trace e, in place
  __shared__ float sh_wz[2][512], sh_wdv[2][512];   // pre-scaled Wh rows (z, dv)
  __shared__ float sh_xz[2][512], sh_xdv[2][512];   // pre-scaled Wx rows (z, dv)
  __shared__ float sh_al[2][512];                   // alpha rows
  __shared__ float sh_up[2][512], sh_lo[2][512];    // clip bounds (precomputed)
  __shared__ float sh_gates[8][4];

  const int tid = threadIdx.x;
  const int w = tid >> 6, L = tid & 63;
  const int b = w & 7, ii = w >> 3;
  const int i0 = blockIdx.x * 2;
  const int i = i0 + ii;

  // ---- one-time staging ----
#pragma unroll
  for (int k = 0; k < 4; k++) {
    int e = tid + k * 1024;
    sh_h[e] = h0[e];
    sh_te[e] = te0[e];
  }
  {
    int jj = tid >> 9, c = tid & 511;
    int rz = i0 + jj, rdv = 1024 + i0 + jj, rr = 512 + i0 + jj;
    sh_wz[jj][c]  = sch[rz]  * h2h_v[(size_t)rz  * 512 + c];
    sh_wdv[jj][c] = sch[rdv] * h2h_v[(size_t)rdv * 512 + c];
    sh_xz[jj][c]  = scx[rz]  * x2h_v[(size_t)rz  * 512 + c];
    sh_xdv[jj][c] = scx[rdv] * x2h_v[(size_t)rdv * 512 + c];
    float al = alpha[(size_t)rz * 512 + c];
    sh_al[jj][c] = al;
    float wr = sch[rr] * h2h_v[(size_t)rr * 512 + c];
    float inv = 1.f / (al + 1e-5f);
    sh_up[jj][c] = fmaxf(1.f - wr, 0.f) * inv;
    sh_lo[jj][c] = -fmaxf(1.f + wr, 0.f) * inv;
  }

  // ---- state into registers ----
  float dUreg[8], tEreg[8], mwreg[8], mbreg[8];
  const size_t row  = ((size_t)(b * 512 + i)) * 512;
  const size_t wrow = (size_t)i * 512;
#pragma unroll
  for (int m = 0; m < 8; m++) {
    int j = m * 64 + L;
    dUreg[m] = dU0[row + j];
    tEreg[m] = tE0[row + j];
    mwreg[m] = modU_w[wrow + j];
    mbreg[m] = modU_b[wrow + j];
  }
  float v_reg = 0.f, hn_last = 0.f, bz = 0.f, bdv = 0.f;
  if (L == 0) {
    v_reg = v0[b * 512 + i];
    bz  = x2h_b[i] + h2h_b[i];
    bdv = x2h_b[1024 + i] + h2h_b[1024 + i];
  }
  __syncthreads();

  cg::grid_group grid = cg::this_grid();

  for (int t = 0; t <= 32; t++) {
    if (t > 0) {
      grid.sync();
      const float* hcur_g = o_outs + (size_t)(t - 1) * 4096;  // h_t
      // gates: mod = h_t @ h2mod_w.T + h2mod_b (waves 0..7, one batch each)
      if (w < 8) {
        float p0 = 0, p1 = 0, p2 = 0, p3 = 0;
        const float* hb = hcur_g + w * 512;
#pragma unroll
        for (int m = 0; m < 8; m++) {
          int c = m * 64 + L;
          float hv_ = hb[c];
          p0 = fmaf(hv_, h2mod_w[c], p0);
          p1 = fmaf(hv_, h2mod_w[512 + c], p1);
          p2 = fmaf(hv_, h2mod_w[1024 + c], p2);
          p3 = fmaf(hv_, h2mod_w[1536 + c], p3);
        }
        p0 = wred(p0); p1 = wred(p1); p2 = wred(p2); p3 = wred(p3);
        if (L == 0) {
          sh_gates[w][0] = sigm(p0 + h2mod_b[0]);
          sh_gates[w][1] = sigm(p1 + h2mod_b[1]);
          sh_gates[w][2] = sigm(p2 + h2mod_b[2]);
          sh_gates[w][3] = fmaxf(p3 + h2mod_b[3], 0.f);
        }
      }
      __syncthreads();
      // te_n = te + tau_e*(h_{t-1} - te); sh_h still holds h_{t-1}
#pragma unroll
      for (int k = 0; k < 4; k++) {
        int e = tid + k * 1024;
        float taue = sh_gates[e >> 9][0];
        sh_te[e] += taue * (sh_h[e] - sh_te[e]);
      }
      __syncthreads();
      // overwrite sh_h with h_t
#pragma unroll
      for (int k = 0; k < 4; k++) {
        int e = tid + k * 1024;
        sh_h[e] = hcur_g[e];
      }
      __syncthreads();
      // tE/dU update for owned rows (registers)
      float tauE = sh_gates[b][1], tauU = sh_gates[b][2], mU = sh_gates[b][3];
      float hn_i = sh_h[b * 512 + i];
      float te_i = sh_te[b * 512 + i];
#pragma unroll
      for (int m = 0; m < 8; m++) {
        int j = m * 64 + L;
        float te_j = sh_te[b * 512 + j];
        float hn_j = sh_h[b * 512 + j];
        float outer = hn_i * te_j - te_i * hn_j;
        float tEn = tEreg[m] + tauE * (outer - tEreg[m]);
        float a = fmaf(mU, mwreg[m], mbreg[m]);
        float sshr = (a > 0.5f) ? (a - 0.5f) : ((a < -0.5f) ? (a + 0.5f) : 0.f);
        float dUn = dUreg[m] + tauU * (sshr * tEn - dUreg[m]);
        dUn = fminf(fmaxf(dUn, sh_lo[ii][j]), sh_up[ii][j]);
        tEreg[m] = tEn;
        dUreg[m] = dUn;
      }
    }

    if (t < 32) {
      // z/dv row-dots for step t, using sh_h = h_t and register dU
      const float* xrow = x + (size_t)t * 4096 + b * 512;
      float p1 = 0.f, p2 = 0.f;
#pragma unroll
      for (int m = 0; m < 8; m++) {
        int c = m * 64 + L;
        float hc = sh_h[b * 512 + c];
        float xc = xrow[c];
        p1 += sh_wz[ii][c] * hc + sh_xz[ii][c] * xc;
        p2 += sh_wdv[ii][c] * hc + sh_xdv[ii][c] * xc + sh_al[ii][c] * dUreg[m] * hc;
      }
      p1 = wred(p1); p2 = wred(p2);
      if (L == 0) {
        float z = sigm(p1 + bz);
        float dv = p2 + bdv;
        v_reg += z * (dv - v_reg);
        hn_last = fmaxf(v_reg, 0.f);
        o_outs[(size_t)t * 4096 + b * 512 + i] = hn_last;
      }
    }
  }

  // ---- final writes ----
#pragma unroll
  for (int m = 0; m < 8; m++) {
    int j = m * 64 + L;
    o_dU[row + j] = dUreg[m];
    o_tE[row + j] = tEreg[m];
  }
  if (L == 0) {
    o_v[b * 512 + i] = v_reg;
    o_h[b * 512 + i] = hn_last;
  }
  if (tid < 16) {
    int e = blockIdx.x * 16 + tid;
    o_te[e] = sh_te[e];
  }
}

extern "C" void kernel_launch(void* const* d_in, const int* in_sizes, int n_in,
                              void* d_out, int out_size, void* d_ws, size_t ws_size,
                              hipStream_t stream) {
  const float* x       = (const float*)d_in[0];
  const float* h0      = (const float*)d_in[1];
  const float* v0      = (const float*)d_in[2];
  const float* dU0     = (const float*)d_in[3];
  const float* te0     = (const float*)d_in[4];
  const float* tE0     = (const float*)d_in[5];
  const float* x2h_v   = (const float*)d_in[6];
  const float* x2h_g   = (const float*)d_in[7];
  const float* x2h_b   = (const float*)d_in[8];
  const float* h2h_v   = (const float*)d_in[9];
  const float* h2h_g   = (const float*)d_in[10];
  const float* h2h_b   = (const float*)d_in[11];
  const float* alpha   = (const float*)d_in[12];
  const float* h2mod_w = (const float*)d_in[13];
  const float* h2mod_b = (const float*)d_in[14];
  const float* modU_w  = (const float*)d_in[15];
  const float* modU_b  = (const float*)d_in[16];

  float* out = (float*)d_out;
  // output layout: v(4096) h(4096) dU(2097152) te(4096) tE(2097152) outs(131072)
  float* o_v    = out;
  float* o_h    = out + 4096;
  float* o_dU   = out + 8192;
  float* o_te   = out + 2105344;
  float* o_tE   = out + 2109440;
  float* o_outs = out + 4206592;

  float* wsf = (float*)d_ws;
  float* scx = wsf;         // 1536
  float* sch = wsf + 1536;  // 1536

  prenorm_kernel<<<dim3(3072), dim3(64), 0, stream>>>(x2h_v, x2h_g, h2h_v, h2h_g, scx, sch);

  void* kargs[] = {
      (void*)&x, (void*)&h0, (void*)&v0, (void*)&dU0, (void*)&te0, (void*)&tE0,
      (void*)&x2h_v, (void*)&x2h_b, (void*)&h2h_v, (void*)&h2h_b, (void*)&alpha,
      (void*)&h2mod_w, (void*)&h2mod_b, (void*)&modU_w, (void*)&modU_b,
      (void*)&scx, (void*)&sch,
      (void*)&o_v, (void*)&o_h, (void*)&o_dU, (void*)&o_te, (void*)&o_tE, (void*)&o_outs};
  hipLaunchCooperativeKernel((void*)persist_kernel, dim3(256), dim3(1024), kargs, 0, stream);
}

// Round 3
// 534.380 us; speedup vs baseline: 2.3629x; 2.3629x over previous
//
#include <hip/hip_runtime.h>
#include <math.h>

// SGRUCell T=32 B=8 I=512 H=512, all f32.
// Persistent kernel, batch-decomposed: block (q = blk>>3, b = blk&7) owns rows
// i in [16q, 16q+16) of batch b. dU/tE/weights in registers (88 VGPRs), h/te
// for the block's batch in LDS (4 KB). The 8 batch chains are independent:
// each syncs via its own 32-block hand-rolled barrier (leader-only arrive,
// relaxed spin + s_sleep, single acquire fence on exit) -- replaces CG
// grid.sync() which cost ~36 us/step in round 2.

__device__ __forceinline__ float wred(float v) {
#pragma unroll
  for (int o = 32; o > 0; o >>= 1) v += __shfl_xor(v, o, 64);
  return v;
}
__device__ __forceinline__ float sigm(float x) { return 1.f / (1.f + __expf(-x)); }

// barrier state: 8 groups x 64 u32 (256 B apart); cnt at +0, gen at +32.
__device__ __forceinline__ void gbar(unsigned* cnt, unsigned* gen, unsigned stepv) {
  __syncthreads();  // all waves' h-stores issued & drained before leader arrives
  if (threadIdx.x == 0) {
    __builtin_amdgcn_fence(__ATOMIC_RELEASE, "agent");
    unsigned old = __hip_atomic_fetch_add(cnt, 1u, __ATOMIC_RELAXED,
                                          __HIP_MEMORY_SCOPE_AGENT);
    if (old == stepv * 32u - 1u) {
      __hip_atomic_store(gen, stepv, __ATOMIC_RELAXED, __HIP_MEMORY_SCOPE_AGENT);
    } else {
      unsigned g;
      do {
        __builtin_amdgcn_s_sleep(1);
        g = __hip_atomic_load(gen, __ATOMIC_RELAXED, __HIP_MEMORY_SCOPE_AGENT);
      } while (g < stepv);
    }
    __builtin_amdgcn_fence(__ATOMIC_ACQUIRE, "agent");
  }
  __syncthreads();
}

__global__ void prenorm_kernel(const float* __restrict__ xv, const float* __restrict__ xg,
                               const float* __restrict__ hv, const float* __restrict__ hg,
                               float* __restrict__ scx, float* __restrict__ sch,
                               unsigned* __restrict__ bar) {
  int r = blockIdx.x, L = threadIdx.x;
  if (r == 0) {  // zero barrier state (ws is re-poisoned 0xAA before every launch)
#pragma unroll
    for (int k = 0; k < 8; k++) bar[k * 64 + L] = 0u;
  }
  const float* vrow; const float* g; float* o; int rr;
  if (r < 1536) { rr = r; vrow = xv + (size_t)r * 512; g = xg; o = scx; }
  else { rr = r - 1536; vrow = hv + (size_t)rr * 512; g = hg; o = sch; }
  float s = 0.f;
#pragma unroll
  for (int m = 0; m < 8; m++) { float v = vrow[m * 64 + L]; s = fmaf(v, v, s); }
  s = wred(s);
  if (L == 0) o[rr] = g[rr] / sqrtf(s);
}

__global__ __launch_bounds__(1024, 4) void persist_kernel(
    const float* __restrict__ x,
    const float* __restrict__ h0, const float* __restrict__ v0,
    const float* __restrict__ dU0, const float* __restrict__ te0,
    const float* __restrict__ tE0,
    const float* __restrict__ x2h_v, const float* __restrict__ x2h_b,
    const float* __restrict__ h2h_v, const float* __restrict__ h2h_b,
    const float* __restrict__ alpha,
    const float* __restrict__ h2mod_w, const float* __restrict__ h2mod_b,
    const float* __restrict__ modU_w, const float* __restrict__ modU_b,
    const float* __restrict__ scx, const float* __restrict__ sch,
    unsigned* __restrict__ bar,
    float* __restrict__ o_v, float* __restrict__ o_h,
    float* __restrict__ o_dU, float* __restrict__ o_te,
    float* __restrict__ o_tE, float* __restrict__ o_outs) {
  __shared__ float sh_h[512];    // h_t for this batch
  __shared__ float sh_te[512];   // eligibility trace for this batch
  __shared__ float sh_gates[4];  // tau_e, tau_E, tau_U, mU

  const int tid = threadIdx.x;
  const int w = tid >> 6, L = tid & 63;
  const int b = blockIdx.x & 7, q = blockIdx.x >> 3;
  const int i = q * 16 + w;  // owned row
  unsigned* cnt = bar + b * 64;
  unsigned* gen = cnt + 32;

  // ---- one-time staging ----
  if (tid < 512) {
    sh_h[tid] = h0[b * 512 + tid];
    sh_te[tid] = te0[b * 512 + tid];
  }
  float wz[8], wdv[8], xz[8], xdv[8], al[8], up[8], lo[8], mw[8], mb[8], dU[8], tE[8];
  const int rz = i, rdv = 1024 + i, rr = 512 + i;
  const float s_z = sch[rz], s_dv = sch[rdv], s_r = sch[rr];
  const float sx_z = scx[rz], sx_dv = scx[rdv];
  const size_t row = ((size_t)(b * 512 + i)) * 512;
#pragma unroll
  for (int m = 0; m < 8; m++) {
    int c = m * 64 + L;
    wz[m]  = s_z  * h2h_v[(size_t)rz  * 512 + c];
    wdv[m] = s_dv * h2h_v[(size_t)rdv * 512 + c];
    xz[m]  = sx_z  * x2h_v[(size_t)rz  * 512 + c];
    xdv[m] = sx_dv * x2h_v[(size_t)rdv * 512 + c];
    float a = alpha[(size_t)i * 512 + c];
    al[m] = a;
    float wrv = s_r * h2h_v[(size_t)rr * 512 + c];
    float inv = 1.f / (a + 1e-5f);
    up[m] = fmaxf(1.f - wrv, 0.f) * inv;
    lo[m] = -fmaxf(1.f + wrv, 0.f) * inv;
    mw[m] = modU_w[(size_t)i * 512 + c];
    mb[m] = modU_b[(size_t)i * 512 + c];
    dU[m] = dU0[row + c];
    tE[m] = tE0[row + c];
  }
  float v_reg = 0.f, hn_last = 0.f, bz = 0.f, bdv = 0.f;
  if (L == 0) {
    v_reg = v0[b * 512 + i];
    bz  = x2h_b[i] + h2h_b[i];
    bdv = x2h_b[1024 + i] + h2h_b[1024 + i];
  }
  __syncthreads();

  for (int t = 0; t <= 32; t++) {
    if (t > 0) {
      gbar(cnt, gen, (unsigned)t);
      const float* hg = o_outs + (size_t)(t - 1) * 4096 + b * 512;  // h_t
      // gates: mod = h_t @ h2mod_w.T + h2mod_b, one wave per output
      if (w < 4) {
        float p = 0.f;
        const float* mrow = h2mod_w + w * 512;
#pragma unroll
        for (int m = 0; m < 8; m++) {
          int c = m * 64 + L;
          p = fmaf(hg[c], mrow[c], p);
        }
        p = wred(p);
        if (L == 0) {
          p += h2mod_b[w];
          sh_gates[w] = (w == 3) ? fmaxf(p, 0.f) : sigm(p);
        }
      }
      __syncthreads();
      // te_n = te + tau_e*(h_{t-1} - te); sh_h still holds h_{t-1}
      float taue = sh_gates[0];
      if (tid < 512) sh_te[tid] += taue * (sh_h[tid] - sh_te[tid]);
      __syncthreads();
      if (tid < 512) sh_h[tid] = hg[tid];  // overwrite with h_t
      __syncthreads();
      // tE/dU register update for owned row
      float tauE = sh_gates[1], tauU = sh_gates[2], mU = sh_gates[3];
      float hn_i = sh_h[i], te_i = sh_te[i];
#pragma unroll
      for (int m = 0; m < 8; m++) {
        int j = m * 64 + L;
        float outer = hn_i * sh_te[j] - te_i * sh_h[j];
        float tEn = tE[m] + tauE * (outer - tE[m]);
        float a = fmaf(mU, mw[m], mb[m]);
        float sshr = (a > 0.5f) ? (a - 0.5f) : ((a < -0.5f) ? (a + 0.5f) : 0.f);
        float dUn = dU[m] + tauU * (sshr * tEn - dU[m]);
        dU[m] = fminf(fmaxf(dUn, lo[m]), up[m]);
        tE[m] = tEn;
      }
    }

    if (t < 32) {
      // z/dv dots for step t using sh_h = h_t and register dU
      const float* xrow = x + (size_t)t * 4096 + b * 512;
      float p1 = 0.f, p2 = 0.f;
#pragma unroll
      for (int m = 0; m < 8; m++) {
        int c = m * 64 + L;
        float hc = sh_h[c];
        float xc = xrow[c];
        p1 += wz[m] * hc + xz[m] * xc;
        p2 += wdv[m] * hc + xdv[m] * xc + al[m] * dU[m] * hc;
      }
      p1 = wred(p1); p2 = wred(p2);
      if (L == 0) {
        float z = sigm(p1 + bz);
        float dv = p2 + bdv;
        v_reg += z * (dv - v_reg);
        hn_last = fmaxf(v_reg, 0.f);
        o_outs[(size_t)t * 4096 + b * 512 + i] = hn_last;
      }
    }
  }

  // ---- final writes ----
#pragma unroll
  for (int m = 0; m < 8; m++) {
    int c = m * 64 + L;
    o_dU[row + c] = dU[m];
    o_tE[row + c] = tE[m];
  }
  if (L == 0) {
    o_v[b * 512 + i] = v_reg;
    o_h[b * 512 + i] = hn_last;
  }
  if (q == 0 && tid < 512) o_te[b * 512 + tid] = sh_te[tid];
}

extern "C" void kernel_launch(void* const* d_in, const int* in_sizes, int n_in,
                              void* d_out, int out_size, void* d_ws, size_t ws_size,
                              hipStream_t stream) {
  const float* x       = (const float*)d_in[0];
  const float* h0      = (const float*)d_in[1];
  const float* v0      = (const float*)d_in[2];
  const float* dU0     = (const float*)d_in[3];
  const float* te0     = (const float*)d_in[4];
  const float* tE0     = (const float*)d_in[5];
  const float* x2h_v   = (const float*)d_in[6];
  const float* x2h_g   = (const float*)d_in[7];
  const float* x2h_b   = (const float*)d_in[8];
  const float* h2h_v   = (const float*)d_in[9];
  const float* h2h_g   = (const float*)d_in[10];
  const float* h2h_b   = (const float*)d_in[11];
  const float* alpha   = (const float*)d_in[12];
  const float* h2mod_w = (const float*)d_in[13];
  const float* h2mod_b = (const float*)d_in[14];
  const float* modU_w  = (const float*)d_in[15];
  const float* modU_b  = (const float*)d_in[16];

  float* out = (float*)d_out;
  // output layout: v(4096) h(4096) dU(2097152) te(4096) tE(2097152) outs(131072)
  float* o_v    = out;
  float* o_h    = out + 4096;
  float* o_dU   = out + 8192;
  float* o_te   = out + 2105344;
  float* o_tE   = out + 2109440;
  float* o_outs = out + 4206592;

  unsigned* bar = (unsigned*)d_ws;       // 512 u32 (8 groups x 256 B)
  float* wsf = (float*)d_ws;
  float* scx = wsf + 512;                // 1536
  float* sch = wsf + 2048;               // 1536

  prenorm_kernel<<<dim3(3072), dim3(64), 0, stream>>>(x2h_v, x2h_g, h2h_v, h2h_g,
                                                      scx, sch, bar);

  void* kargs[] = {
      (void*)&x, (void*)&h0, (void*)&v0, (void*)&dU0, (void*)&te0, (void*)&tE0,
      (void*)&x2h_v, (void*)&x2h_b, (void*)&h2h_v, (void*)&h2h_b, (void*)&alpha,
      (void*)&h2mod_w, (void*)&h2mod_b, (void*)&modU_w, (void*)&modU_b,
      (void*)&scx, (void*)&sch, (void*)&bar,
      (void*)&o_v, (void*)&o_h, (void*)&o_dU, (void*)&o_te, (void*)&o_tE, (void*)&o_outs};
  hipLaunchCooperativeKernel((void*)persist_kernel, dim3(256), dim3(1024), kargs, 0, stream);
}

// Round 4
// 342.973 us; speedup vs baseline: 3.6816x; 1.5581x over previous
//
#include <hip/hip_runtime.h>
#include <math.h>

// SGRUCell T=32 B=8 I=512 H=512, all f32.
// Persistent kernel, batch-decomposed: block (q = blk>>3, b = blk&7) owns rows
// i in [16q, 16q+16) of batch b. dU/tE/weights in registers, h/te in LDS.
// Cross-block sync is pure data-flow: h values are exchanged through per-step
// slots in d_ws, written as (h + 1.0) [always >= 1.0] with relaxed agent-scope
// atomic stores and polled with relaxed agent-scope atomic loads until
// >= 0.5. Sentinels (0x00000000 memset, 0xAAAAAAAA poison) decode < 0.5.
// No fences -> no per-step L1/L2 invalidation (round-3's 13 us/step killer).

__device__ __forceinline__ float wred(float v) {
#pragma unroll
  for (int o = 32; o > 0; o >>= 1) v += __shfl_xor(v, o, 64);
  return v;
}
__device__ __forceinline__ float sigm(float x) { return 1.f / (1.f + __expf(-x)); }

__global__ void prenorm_kernel(const float* __restrict__ xv, const float* __restrict__ xg,
                               const float* __restrict__ hv, const float* __restrict__ hg,
                               float* __restrict__ scx, float* __restrict__ sch,
                               unsigned* __restrict__ hx) {
  int r = blockIdx.x, L = threadIdx.x;
  if (r < 2048) hx[r * 64 + L] = 0u;  // clear 32x4096 exchange slots
  const float* vrow; const float* g; float* o; int rr;
  if (r < 1536) { rr = r; vrow = xv + (size_t)r * 512; g = xg; o = scx; }
  else { rr = r - 1536; vrow = hv + (size_t)rr * 512; g = hg; o = sch; }
  float s = 0.f;
#pragma unroll
  for (int m = 0; m < 8; m++) { float v = vrow[m * 64 + L]; s = fmaf(v, v, s); }
  s = wred(s);
  if (L == 0) o[rr] = g[rr] / sqrtf(s);
}

__global__ __launch_bounds__(1024, 4) void persist_kernel(
    const float* __restrict__ x,
    const float* __restrict__ h0, const float* __restrict__ v0,
    const float* __restrict__ dU0, const float* __restrict__ te0,
    const float* __restrict__ tE0,
    const float* __restrict__ x2h_v, const float* __restrict__ x2h_b,
    const float* __restrict__ h2h_v, const float* __restrict__ h2h_b,
    const float* __restrict__ alpha,
    const float* __restrict__ h2mod_w, const float* __restrict__ h2mod_b,
    const float* __restrict__ modU_w, const float* __restrict__ modU_b,
    const float* __restrict__ scx, const float* __restrict__ sch,
    unsigned* __restrict__ hx,
    float* __restrict__ o_v, float* __restrict__ o_h,
    float* __restrict__ o_dU, float* __restrict__ o_te,
    float* __restrict__ o_tE, float* __restrict__ o_outs) {
  __shared__ float sh_hbuf[2][512];  // h ping-pong: buf[t&1] = h_t
  __shared__ float sh_te[512];       // eligibility trace for this batch
  __shared__ float sh_gates[4];      // tau_e, tau_E, tau_U, mU

  const int tid = threadIdx.x;
  const int w = tid >> 6, L = tid & 63;
  const int b = blockIdx.x & 7, q = blockIdx.x >> 3;
  const int i = q * 16 + w;  // owned row

  // ---- one-time staging ----
  if (tid < 512) {
    sh_hbuf[0][tid] = h0[b * 512 + tid];
    sh_te[tid] = te0[b * 512 + tid];
  }
  float wz[8], wdv[8], xz[8], xdv[8], al[8], up[8], lo[8], mw[8], mb[8], dU[8], tE[8];
  const int rz = i, rdv = 1024 + i, rr = 512 + i;
  const float s_z = sch[rz], s_dv = sch[rdv], s_r = sch[rr];
  const float sx_z = scx[rz], sx_dv = scx[rdv];
  const size_t row = ((size_t)(b * 512 + i)) * 512;
#pragma unroll
  for (int m = 0; m < 8; m++) {
    int c = m * 64 + L;
    wz[m]  = s_z  * h2h_v[(size_t)rz  * 512 + c];
    wdv[m] = s_dv * h2h_v[(size_t)rdv * 512 + c];
    xz[m]  = sx_z  * x2h_v[(size_t)rz  * 512 + c];
    xdv[m] = sx_dv * x2h_v[(size_t)rdv * 512 + c];
    float a = alpha[(size_t)i * 512 + c];
    al[m] = a;
    float wrv = s_r * h2h_v[(size_t)rr * 512 + c];
    float inv = 1.f / (a + 1e-5f);
    up[m] = fmaxf(1.f - wrv, 0.f) * inv;
    lo[m] = -fmaxf(1.f + wrv, 0.f) * inv;
    mw[m] = modU_w[(size_t)i * 512 + c];
    mb[m] = modU_b[(size_t)i * 512 + c];
    dU[m] = dU0[row + c];
    tE[m] = tE0[row + c];
  }
  float v_reg = 0.f, hn_last = 0.f, bz = 0.f, bdv = 0.f;
  if (L == 0) {
    v_reg = v0[b * 512 + i];
    bz  = x2h_b[i] + h2h_b[i];
    bdv = x2h_b[1024 + i] + h2h_b[1024 + i];
  }
  __syncthreads();

  for (int t = 0; t <= 32; t++) {
    const int cur = t & 1, prev = cur ^ 1;
    if (t > 0) {
      // stage h_t: poll per-element exchange slots (data-flow sync, no fences)
      if (tid < 512) {
        unsigned* slot = hx + (size_t)(t - 1) * 4096 + b * 512 + tid;
        unsigned u;
        do {
          u = __hip_atomic_load(slot, __ATOMIC_RELAXED, __HIP_MEMORY_SCOPE_AGENT);
        } while (__uint_as_float(u) < 0.5f);
        sh_hbuf[cur][tid] = __uint_as_float(u) - 1.0f;
      }
      __syncthreads();
      // gates: mod = h_t @ h2mod_w.T + h2mod_b, one wave per output
      if (w < 4) {
        float p = 0.f;
        const float* mrow = h2mod_w + w * 512;
#pragma unroll
        for (int m = 0; m < 8; m++) {
          int c = m * 64 + L;
          p = fmaf(sh_hbuf[cur][c], mrow[c], p);
        }
        p = wred(p);
        if (L == 0) {
          p += h2mod_b[w];
          sh_gates[w] = (w == 3) ? fmaxf(p, 0.f) : sigm(p);
        }
      }
      __syncthreads();
      // te_n = te + tau_e*(h_{t-1} - te); buf[prev] holds h_{t-1}
      float taue = sh_gates[0];
      if (tid < 512) sh_te[tid] += taue * (sh_hbuf[prev][tid] - sh_te[tid]);
      __syncthreads();
      // tE/dU register update for owned row
      float tauE = sh_gates[1], tauU = sh_gates[2], mU = sh_gates[3];
      float hn_i = sh_hbuf[cur][i], te_i = sh_te[i];
#pragma unroll
      for (int m = 0; m < 8; m++) {
        int j = m * 64 + L;
        float outer = hn_i * sh_te[j] - te_i * sh_hbuf[cur][j];
        float tEn = tE[m] + tauE * (outer - tE[m]);
        float a = fmaf(mU, mw[m], mb[m]);
        float sshr = (a > 0.5f) ? (a - 0.5f) : ((a < -0.5f) ? (a + 0.5f) : 0.f);
        float dUn = dU[m] + tauU * (sshr * tEn - dU[m]);
        dU[m] = fminf(fmaxf(dUn, lo[m]), up[m]);
        tE[m] = tEn;
      }
    }

    if (t < 32) {
      // z/dv dots for step t using buf[cur] = h_t and register dU
      const float* xrow = x + (size_t)t * 4096 + b * 512;
      float p1 = 0.f, p2 = 0.f;
#pragma unroll
      for (int m = 0; m < 8; m++) {
        int c = m * 64 + L;
        float hc = sh_hbuf[cur][c];
        float xc = xrow[c];
        p1 += wz[m] * hc + xz[m] * xc;
        p2 += wdv[m] * hc + xdv[m] * xc + al[m] * dU[m] * hc;
      }
      p1 = wred(p1); p2 = wred(p2);
      if (L == 0) {
        float z = sigm(p1 + bz);
        float dv = p2 + bdv;
        v_reg += z * (dv - v_reg);
        hn_last = fmaxf(v_reg, 0.f);
        o_outs[(size_t)t * 4096 + b * 512 + i] = hn_last;
        __hip_atomic_store(hx + (size_t)t * 4096 + b * 512 + i,
                           __float_as_uint(hn_last + 1.0f),
                           __ATOMIC_RELAXED, __HIP_MEMORY_SCOPE_AGENT);
      }
    }
  }

  // ---- final writes ----
#pragma unroll
  for (int m = 0; m < 8; m++) {
    int c = m * 64 + L;
    o_dU[row + c] = dU[m];
    o_tE[row + c] = tE[m];
  }
  if (L == 0) {
    o_v[b * 512 + i] = v_reg;
    o_h[b * 512 + i] = hn_last;
  }
  if (q == 0 && tid < 512) o_te[b * 512 + tid] = sh_te[tid];
}

extern "C" void kernel_launch(void* const* d_in, const int* in_sizes, int n_in,
                              void* d_out, int out_size, void* d_ws, size_t ws_size,
                              hipStream_t stream) {
  const float* x       = (const float*)d_in[0];
  const float* h0      = (const float*)d_in[1];
  const float* v0      = (const float*)d_in[2];
  const float* dU0     = (const float*)d_in[3];
  const float* te0     = (const float*)d_in[4];
  const float* tE0     = (const float*)d_in[5];
  const float* x2h_v   = (const float*)d_in[6];
  const float* x2h_g   = (const float*)d_in[7];
  const float* x2h_b   = (const float*)d_in[8];
  const float* h2h_v   = (const float*)d_in[9];
  const float* h2h_g   = (const float*)d_in[10];
  const float* h2h_b   = (const float*)d_in[11];
  const float* alpha   = (const float*)d_in[12];
  const float* h2mod_w = (const float*)d_in[13];
  const float* h2mod_b = (const float*)d_in[14];
  const float* modU_w  = (const float*)d_in[15];
  const float* modU_b  = (const float*)d_in[16];

  float* out = (float*)d_out;
  // output layout: v(4096) h(4096) dU(2097152) te(4096) tE(2097152) outs(131072)
  float* o_v    = out;
  float* o_h    = out + 4096;
  float* o_dU   = out + 8192;
  float* o_te   = out + 2105344;
  float* o_tE   = out + 2109440;
  float* o_outs = out + 4206592;

  unsigned* hx = (unsigned*)d_ws;        // 32*4096 u32 exchange slots (512 KB)
  float* wsf = (float*)d_ws;
  float* scx = wsf + 131072;             // 1536
  float* sch = wsf + 132608;             // 1536

  prenorm_kernel<<<dim3(3072), dim3(64), 0, stream>>>(x2h_v, x2h_g, h2h_v, h2h_g,
                                                      scx, sch, hx);

  persist_kernel<<<dim3(256), dim3(1024), 0, stream>>>(
      x, h0, v0, dU0, te0, tE0, x2h_v, x2h_b, h2h_v, h2h_b, alpha,
      h2mod_w, h2mod_b, modU_w, modU_b, scx, sch, hx,
      o_v, o_h, o_dU, o_te, o_tE, o_outs);
}

// Round 5
// 323.193 us; speedup vs baseline: 3.9070x; 1.0612x over previous
//
#include <hip/hip_runtime.h>
#include <math.h>

// SGRUCell T=32 B=8 I=512 H=512, all f32.
// Persistent kernel: block (q=blk>>3, b=blk&7) owns rows i in [16q,16q+16) of
// batch b; 16 waves, one row per wave. dU/tE (+ dUs=alpha*dU) in registers
// (40 persistent VGPRs -- round-4's 11 arrays spilled to scratch: 39.5 MB
// WRITE_SIZE anomaly). Update-phase tables (modU_w/b, alpha, Wr) re-read from
// global each step (L2-resident). x-projection precomputed for all 32 steps
// (h-independent) into LDS. Cross-block sync: producers atomic-store h bits,
// per-wave s_waitcnt, leader fetch_add on per-(step,batch) counter; ONE
// consumer thread polls the counter to 32, then h read once via relaxed
// agent atomics (no fences, no poll storm).

__device__ __forceinline__ float wred(float v) {
#pragma unroll
  for (int o = 32; o > 0; o >>= 1) v += __shfl_xor(v, o, 64);
  return v;
}
__device__ __forceinline__ float sigm(float x) { return 1.f / (1.f + __expf(-x)); }

__global__ void prenorm_kernel(const float* __restrict__ xv, const float* __restrict__ xg,
                               const float* __restrict__ hv, const float* __restrict__ hg,
                               float* __restrict__ scx, float* __restrict__ sch,
                               unsigned* __restrict__ cnt) {
  int r = blockIdx.x, L = threadIdx.x;
  if (r == 0) {  // clear 32x8 step counters (64B-spaced); ws is poisoned 0xAA
#pragma unroll
    for (int k = 0; k < 64; k++) cnt[k * 64 + L] = 0u;
  }
  const float* vrow; const float* g; float* o; int rr;
  if (r < 1536) { rr = r; vrow = xv + (size_t)r * 512; g = xg; o = scx; }
  else { rr = r - 1536; vrow = hv + (size_t)rr * 512; g = hg; o = sch; }
  float s = 0.f;
#pragma unroll
  for (int m = 0; m < 8; m++) { float v = vrow[m * 64 + L]; s = fmaf(v, v, s); }
  s = wred(s);
  if (L == 0) o[rr] = g[rr] / sqrtf(s);
}

__global__ __launch_bounds__(1024, 4) void persist_kernel(
    const float* __restrict__ x,
    const float* __restrict__ h0, const float* __restrict__ v0,
    const float* __restrict__ dU0, const float* __restrict__ te0,
    const float* __restrict__ tE0,
    const float* __restrict__ x2h_v, const float* __restrict__ x2h_b,
    const float* __restrict__ h2h_v, const float* __restrict__ h2h_b,
    const float* __restrict__ alpha,
    const float* __restrict__ h2mod_w, const float* __restrict__ h2mod_b,
    const float* __restrict__ modU_w, const float* __restrict__ modU_b,
    const float* __restrict__ scx, const float* __restrict__ sch,
    unsigned* __restrict__ hx, unsigned* __restrict__ cnt,
    float* __restrict__ o_v, float* __restrict__ o_h,
    float* __restrict__ o_dU, float* __restrict__ o_te,
    float* __restrict__ o_tE, float* __restrict__ o_outs) {
  __shared__ float sh_hbuf[2][512];   // h ping-pong: buf[t&1] = h_t
  __shared__ float sh_te[512];        // eligibility trace
  __shared__ float sh_mod[2048];      // h2mod_w (4x512)
  __shared__ float sh_xpz[32][16];    // precomputed x-proj (z) + bias, [t][w]
  __shared__ float sh_xpdv[32][16];   // precomputed x-proj (dv) + bias
  __shared__ float sh_gates[4];       // tau_e, tau_E, tau_U, mU

  const int tid = threadIdx.x;
  const int w = tid >> 6, L = tid & 63;
  const int b = blockIdx.x & 7, q = blockIdx.x >> 3;
  const int i = q * 16 + w;  // owned row

  // ---- one-time staging ----
  if (tid < 512) {
    sh_hbuf[0][tid] = h0[b * 512 + tid];
    sh_te[tid] = te0[b * 512 + tid];
  }
  sh_mod[tid] = h2mod_w[tid];
  sh_mod[tid + 1024] = h2mod_w[tid + 1024];

  const int rz = i, rdv = 1024 + i, rr = 512 + i;
  const float s_z = sch[rz], s_dv = sch[rdv], s_r = sch[rr];
  const size_t row  = ((size_t)(b * 512 + i)) * 512;
  const size_t wrow = (size_t)i * 512;    // modU_w/b and alpha row i
  const size_t rrow = (size_t)rr * 512;   // raw Wr row in h2h_v

  float wz[8], wdv[8], dU[8], tE[8], dUs[8];
#pragma unroll
  for (int m = 0; m < 8; m++) {
    int c = m * 64 + L;
    wz[m]  = s_z  * h2h_v[(size_t)rz  * 512 + c];
    wdv[m] = s_dv * h2h_v[(size_t)rdv * 512 + c];
    dU[m] = dU0[row + c];
    tE[m] = tE0[row + c];
    dUs[m] = alpha[wrow + c] * dU[m];
  }
  float v_reg = 0.f, hn_last = 0.f, gb = 0.f;
  if (L == 0) {
    v_reg = v0[b * 512 + i];
    if (w < 4) gb = h2mod_b[w];
  }

  // ---- precompute x-projection for all 32 steps (h-independent) ----
  {
    float xz[8], xdv[8];
    const float sx_z = scx[rz], sx_dv = scx[rdv];
#pragma unroll
    for (int m = 0; m < 8; m++) {
      int c = m * 64 + L;
      xz[m]  = sx_z  * x2h_v[(size_t)rz  * 512 + c];
      xdv[m] = sx_dv * x2h_v[(size_t)rdv * 512 + c];
    }
    float bz = 0.f, bdv = 0.f;
    if (L == 0) {
      bz  = x2h_b[i] + h2h_b[i];
      bdv = x2h_b[1024 + i] + h2h_b[1024 + i];
    }
    for (int t = 0; t < 32; t++) {
      const float* xr = x + (size_t)t * 4096 + b * 512;
      float a = 0.f, d = 0.f;
#pragma unroll
      for (int m = 0; m < 8; m++) {
        int c = m * 64 + L;
        float xv_ = xr[c];
        a = fmaf(xz[m], xv_, a);
        d = fmaf(xdv[m], xv_, d);
      }
      a = wred(a); d = wred(d);
      if (L == 0) { sh_xpz[t][w] = a + bz; sh_xpdv[t][w] = d + bdv; }
    }
  }
  __syncthreads();

  for (int t = 0; t <= 32; t++) {
    const int cur = t & 1, prev = cur ^ 1;
    if (t > 0) {
      // ---- sync in: single poller on the per-(step,batch) counter ----
      if (tid == 0) {
        unsigned* cp = cnt + ((t - 1) * 8 + b) * 16;
        while (__hip_atomic_load(cp, __ATOMIC_RELAXED, __HIP_MEMORY_SCOPE_AGENT) != 32u) {}
      }
      __syncthreads();
      if (tid < 512) {  // one-shot read of h_t (no polling on data)
        unsigned u = __hip_atomic_load(hx + (size_t)(t - 1) * 4096 + b * 512 + tid,
                                       __ATOMIC_RELAXED, __HIP_MEMORY_SCOPE_AGENT);
        sh_hbuf[cur][tid] = __uint_as_float(u);
      }
      __syncthreads();
      // gates: mod = h_t @ h2mod_w.T + b, waves 0..3
      if (w < 4) {
        float p = 0.f;
        const float* mr = sh_mod + w * 512;
#pragma unroll
        for (int m = 0; m < 8; m++) {
          int c = m * 64 + L;
          p = fmaf(sh_hbuf[cur][c], mr[c], p);
        }
        p = wred(p);
        if (L == 0) {
          p += gb;
          sh_gates[w] = (w == 3) ? fmaxf(p, 0.f) : sigm(p);
        }
      }
      __syncthreads();
      // te_n = te + tau_e*(h_{t-1} - te); buf[prev] holds h_{t-1}
      float taue = sh_gates[0];
      if (tid < 512) sh_te[tid] += taue * (sh_hbuf[prev][tid] - sh_te[tid]);
      __syncthreads();
      // tE/dU register update; tables from global (L2-resident)
      float tauE = sh_gates[1], tauU = sh_gates[2], mU = sh_gates[3];
      float hn_i = sh_hbuf[cur][i], te_i = sh_te[i];
#pragma unroll
      for (int m = 0; m < 8; m++) {
        int j = m * 64 + L;
        float mwv = modU_w[wrow + j];
        float mbv = modU_b[wrow + j];
        float alv = alpha[wrow + j];
        float wrv = s_r * h2h_v[rrow + j];
        float outer = hn_i * sh_te[j] - te_i * sh_hbuf[cur][j];
        float tEn = tE[m] + tauE * (outer - tE[m]);
        float a = fmaf(mU, mwv, mbv);
        float sshr = (a > 0.5f) ? (a - 0.5f) : ((a < -0.5f) ? (a + 0.5f) : 0.f);
        float dUn = dU[m] + tauU * (sshr * tEn - dU[m]);
        float inv = __builtin_amdgcn_rcpf(alv + 1e-5f);
        float up_ = fmaxf(1.f - wrv, 0.f) * inv;
        float lo_ = -fmaxf(1.f + wrv, 0.f) * inv;
        dUn = fminf(fmaxf(dUn, lo_), up_);
        dU[m] = dUn;
        tE[m] = tEn;
        dUs[m] = alv * dUn;
      }
    }

    if (t < 32) {
      // z/dv dots for step t (x-part precomputed)
      float p1 = 0.f, p2 = 0.f;
#pragma unroll
      for (int m = 0; m < 8; m++) {
        int c = m * 64 + L;
        float hc = sh_hbuf[cur][c];
        p1 = fmaf(wz[m], hc, p1);
        p2 = fmaf(wdv[m] + dUs[m], hc, p2);
      }
      p1 = wred(p1); p2 = wred(p2);
      if (L == 0) {
        float z = sigm(p1 + sh_xpz[t][w]);
        float dv = p2 + sh_xpdv[t][w];
        v_reg += z * (dv - v_reg);
        hn_last = fmaxf(v_reg, 0.f);
        o_outs[(size_t)t * 4096 + b * 512 + i] = hn_last;
        __hip_atomic_store(hx + (size_t)t * 4096 + b * 512 + i,
                           __float_as_uint(hn_last),
                           __ATOMIC_RELAXED, __HIP_MEMORY_SCOPE_AGENT);
      }
      // each wave drains its own store, then leader announces block arrival
      __builtin_amdgcn_s_waitcnt(0);
      __syncthreads();
      if (tid == 0)
        __hip_atomic_fetch_add(cnt + (t * 8 + b) * 16, 1u, __ATOMIC_RELAXED,
                               __HIP_MEMORY_SCOPE_AGENT);
    }
  }

  // ---- final writes ----
#pragma unroll
  for (int m = 0; m < 8; m++) {
    int c = m * 64 + L;
    o_dU[row + c] = dU[m];
    o_tE[row + c] = tE[m];
  }
  if (L == 0) {
    o_v[b * 512 + i] = v_reg;
    o_h[b * 512 + i] = hn_last;
  }
  if (q == 0 && tid < 512) o_te[b * 512 + tid] = sh_te[tid];
}

extern "C" void kernel_launch(void* const* d_in, const int* in_sizes, int n_in,
                              void* d_out, int out_size, void* d_ws, size_t ws_size,
                              hipStream_t stream) {
  const float* x       = (const float*)d_in[0];
  const float* h0      = (const float*)d_in[1];
  const float* v0      = (const float*)d_in[2];
  const float* dU0     = (const float*)d_in[3];
  const float* te0     = (const float*)d_in[4];
  const float* tE0     = (const float*)d_in[5];
  const float* x2h_v   = (const float*)d_in[6];
  const float* x2h_g   = (const float*)d_in[7];
  const float* x2h_b   = (const float*)d_in[8];
  const float* h2h_v   = (const float*)d_in[9];
  const float* h2h_g   = (const float*)d_in[10];
  const float* h2h_b   = (const float*)d_in[11];
  const float* alpha   = (const float*)d_in[12];
  const float* h2mod_w = (const float*)d_in[13];
  const float* h2mod_b = (const float*)d_in[14];
  const float* modU_w  = (const float*)d_in[15];
  const float* modU_b  = (const float*)d_in[16];

  float* out = (float*)d_out;
  // output layout: v(4096) h(4096) dU(2097152) te(4096) tE(2097152) outs(131072)
  float* o_v    = out;
  float* o_h    = out + 4096;
  float* o_dU   = out + 8192;
  float* o_te   = out + 2105344;
  float* o_tE   = out + 2109440;
  float* o_outs = out + 4206592;

  unsigned* hx  = (unsigned*)d_ws;           // 32*4096 u32 h-exchange (no clear needed)
  unsigned* cnt = hx + 131072;               // 32*8 counters, 64B-spaced (4096 u32)
  float* wsf = (float*)d_ws;
  float* scx = wsf + 135168;                 // 1536
  float* sch = wsf + 136704;                 // 1536

  prenorm_kernel<<<dim3(3072), dim3(64), 0, stream>>>(x2h_v, x2h_g, h2h_v, h2h_g,
                                                      scx, sch, cnt);

  persist_kernel<<<dim3(256), dim3(1024), 0, stream>>>(
      x, h0, v0, dU0, te0, tE0, x2h_v, x2h_b, h2h_v, h2h_b, alpha,
      h2mod_w, h2mod_b, modU_w, modU_b, scx, sch, hx, cnt,
      o_v, o_h, o_dU, o_te, o_tE, o_outs);
}

// Round 6
// 258.114 us; speedup vs baseline: 4.8920x; 1.2521x over previous
//
#include <hip/hip_runtime.h>
#include <math.h>

// SGRUCell T=32 B=8 I=512 H=512, all f32.
// Persistent kernel: block (q=blk>>3, b=blk&7) owns rows i in [16q,16q+16) of
// batch b; 16 waves, one row per wave. ALL per-row tables live in registers:
// wz, wdv, mw, mb, al, upS, loS, D(=alpha*dU), tE  (72 persistent VGPRs) --
// the step loop does zero global table loads (round-5's 32 loads/step).
// x-projection precomputed for all 32 steps into LDS. Cross-block sync:
// producers atomic-store h bits directly into o_outs, s_waitcnt(0), leader
// sets a per-(step,batch,block) flag; consumers poll the 32 packed flags with
// one wave + __all, then read h once via relaxed agent atomics. No fences.

__device__ __forceinline__ float wred(float v) {
#pragma unroll
  for (int o = 32; o > 0; o >>= 1) v += __shfl_xor(v, o, 64);
  return v;
}
__device__ __forceinline__ float sigm(float x) { return 1.f / (1.f + __expf(-x)); }

__global__ void prenorm_kernel(const float* __restrict__ xv, const float* __restrict__ xg,
                               const float* __restrict__ hv, const float* __restrict__ hg,
                               float* __restrict__ scx, float* __restrict__ sch,
                               unsigned* __restrict__ flg) {
  int r = blockIdx.x, L = threadIdx.x;
  if (r < 16) {  // clear 32*8*32 arrival flags (ws is poisoned 0xAA pre-launch)
#pragma unroll
    for (int k = 0; k < 8; k++) flg[r * 512 + k * 64 + L] = 0u;
  }
  const float* vrow; const float* g; float* o; int rr;
  if (r < 1536) { rr = r; vrow = xv + (size_t)r * 512; g = xg; o = scx; }
  else { rr = r - 1536; vrow = hv + (size_t)rr * 512; g = hg; o = sch; }
  float s = 0.f;
#pragma unroll
  for (int m = 0; m < 8; m++) { float v = vrow[m * 64 + L]; s = fmaf(v, v, s); }
  s = wred(s);
  if (L == 0) o[rr] = g[rr] / sqrtf(s);
}

__global__ __launch_bounds__(1024, 4) void persist_kernel(
    const float* __restrict__ x,
    const float* __restrict__ h0, const float* __restrict__ v0,
    const float* __restrict__ dU0, const float* __restrict__ te0,
    const float* __restrict__ tE0,
    const float* __restrict__ x2h_v, const float* __restrict__ x2h_b,
    const float* __restrict__ h2h_v, const float* __restrict__ h2h_b,
    const float* __restrict__ alpha,
    const float* __restrict__ h2mod_w, const float* __restrict__ h2mod_b,
    const float* __restrict__ modU_w, const float* __restrict__ modU_b,
    const float* __restrict__ scx, const float* __restrict__ sch,
    unsigned* __restrict__ flg,
    float* __restrict__ o_v, float* __restrict__ o_h,
    float* __restrict__ o_dU, float* __restrict__ o_te,
    float* __restrict__ o_tE, float* __restrict__ o_outs) {
  __shared__ float sh_hbuf[2][512];   // h ping-pong: buf[t&1] = h_t
  __shared__ float sh_te[512];        // eligibility trace
  __shared__ float sh_mod[2048];      // h2mod_w (4x512)
  __shared__ float sh_xpz[32][16];    // precomputed x-proj (z) + bias, [t][w]
  __shared__ float sh_xpdv[32][16];   // precomputed x-proj (dv) + bias
  __shared__ float sh_gates[4];       // tau_e, tau_E, tau_U, mU

  const int tid = threadIdx.x;
  const int w = tid >> 6, L = tid & 63;
  const int b = blockIdx.x & 7, q = blockIdx.x >> 3;
  const int i = q * 16 + w;  // owned row

  // ---- basic LDS staging ----
  if (tid < 512) {
    sh_hbuf[0][tid] = h0[b * 512 + tid];
    sh_te[tid] = te0[b * 512 + tid];
  }
  sh_mod[tid] = h2mod_w[tid];
  sh_mod[tid + 1024] = h2mod_w[tid + 1024];

  const int rz = i, rdv = 1024 + i, rr = 512 + i;
  const size_t row  = ((size_t)(b * 512 + i)) * 512;
  const size_t wrow = (size_t)i * 512;

  // ---- x-projection precompute FIRST (keeps register pressure low) ----
  {
    float xz[8], xdv[8];
    const float sx_z = scx[rz], sx_dv = scx[rdv];
#pragma unroll
    for (int m = 0; m < 8; m++) {
      int c = m * 64 + L;
      xz[m]  = sx_z  * x2h_v[(size_t)rz  * 512 + c];
      xdv[m] = sx_dv * x2h_v[(size_t)rdv * 512 + c];
    }
    float bz = 0.f, bdv = 0.f;
    if (L == 0) {
      bz  = x2h_b[i] + h2h_b[i];
      bdv = x2h_b[1024 + i] + h2h_b[1024 + i];
    }
#pragma unroll 4
    for (int t = 0; t < 32; t++) {
      const float* xr = x + (size_t)t * 4096 + b * 512;
      float a = 0.f, d = 0.f;
#pragma unroll
      for (int m = 0; m < 8; m++) {
        int c = m * 64 + L;
        float xv_ = xr[c];
        a = fmaf(xz[m], xv_, a);
        d = fmaf(xdv[m], xv_, d);
      }
      a = wred(a); d = wred(d);
      if (L == 0) { sh_xpz[t][w] = a + bz; sh_xpdv[t][w] = d + bdv; }
    }
  }

  // ---- persistent register tables ----
  float wz[8], wdv[8], mw[8], mb[8], al[8], upS[8], loS[8], D[8], tE[8];
  {
    const float s_z = sch[rz], s_dv = sch[rdv], s_r = sch[rr];
#pragma unroll
    for (int m = 0; m < 8; m++) {
      int c = m * 64 + L;
      wz[m]  = s_z  * h2h_v[(size_t)rz  * 512 + c];
      wdv[m] = s_dv * h2h_v[(size_t)rdv * 512 + c];
      mw[m] = modU_w[wrow + c];
      mb[m] = modU_b[wrow + c];
      float alv = alpha[wrow + c];
      al[m] = alv;
      float wrv = s_r * h2h_v[(size_t)rr * 512 + c];
      float t1 = alv / (alv + 1e-5f);   // alpha * (1/(alpha+eps)), prescaled
      upS[m] = fmaxf(1.f - wrv, 0.f) * t1;
      loS[m] = -fmaxf(1.f + wrv, 0.f) * t1;
      float dui = dU0[row + c];
      D[m]  = alv * dui;                // scaled state: D = alpha * dU
      tE[m] = tE0[row + c];
    }
  }
  float v_reg = 0.f, hn_last = 0.f, gb = 0.f;
  if (L == 0) {
    v_reg = v0[b * 512 + i];
    if (w < 4) gb = h2mod_b[w];
  }
  __syncthreads();

  unsigned* hxu = (unsigned*)o_outs;  // h exchanged through the output buffer

  for (int t = 0; t <= 32; t++) {
    const int cur = t & 1, prev = cur ^ 1;
    if (t > 0) {
      // ---- arrival: one wave polls the 32 packed per-block flags ----
      if (w == 0) {
        const unsigned* fp = flg + ((t - 1) * 8 + b) * 32 + (L & 31);
        unsigned u;
        do {
          u = __hip_atomic_load(fp, __ATOMIC_RELAXED, __HIP_MEMORY_SCOPE_AGENT);
        } while (!__all(u != 0u));
      }
      __syncthreads();
      if (tid < 512) {  // one-shot read of h_t
        unsigned u = __hip_atomic_load(hxu + (size_t)(t - 1) * 4096 + b * 512 + tid,
                                       __ATOMIC_RELAXED, __HIP_MEMORY_SCOPE_AGENT);
        sh_hbuf[cur][tid] = __uint_as_float(u);
      }
      __syncthreads();
      // gates: mod = h_t @ h2mod_w.T + b, waves 0..3
      if (w < 4) {
        float p = 0.f;
        const float* mr = sh_mod + w * 512;
#pragma unroll
        for (int m = 0; m < 8; m++) {
          int c = m * 64 + L;
          p = fmaf(sh_hbuf[cur][c], mr[c], p);
        }
        p = wred(p);
        if (L == 0) {
          p += gb;
          sh_gates[w] = (w == 3) ? fmaxf(p, 0.f) : sigm(p);
        }
      }
      __syncthreads();
      // te_n = te + tau_e*(h_{t-1} - te)
      float taue = sh_gates[0];
      if (tid < 512) sh_te[tid] += taue * (sh_hbuf[prev][tid] - sh_te[tid]);
      __syncthreads();
      // tE / D register update (pure VALU, no global loads)
      float tauE = sh_gates[1], tauU = sh_gates[2], mU = sh_gates[3];
      float hn_i = sh_hbuf[cur][i], te_i = sh_te[i];
#pragma unroll
      for (int m = 0; m < 8; m++) {
        int j = m * 64 + L;
        float outer = hn_i * sh_te[j] - te_i * sh_hbuf[cur][j];
        float tEn = tE[m] + tauE * (outer - tE[m]);
        float a = fmaf(mU, mw[m], mb[m]);
        float sshr = (a > 0.5f) ? (a - 0.5f) : ((a < -0.5f) ? (a + 0.5f) : 0.f);
        float Dn = D[m] + tauU * (sshr * (al[m] * tEn) - D[m]);
        D[m] = fminf(fmaxf(Dn, loS[m]), upS[m]);
        tE[m] = tEn;
      }
    }

    if (t < 32) {
      // z/dv dots for step t (x-part precomputed; D = alpha*dU directly)
      float p1 = 0.f, p2 = 0.f;
#pragma unroll
      for (int m = 0; m < 8; m++) {
        int c = m * 64 + L;
        float hc = sh_hbuf[cur][c];
        p1 = fmaf(wz[m], hc, p1);
        p2 = fmaf(wdv[m] + D[m], hc, p2);
      }
      p1 = wred(p1); p2 = wred(p2);
      if (L == 0) {
        float z = sigm(p1 + sh_xpz[t][w]);
        float dv = p2 + sh_xpdv[t][w];
        v_reg += z * (dv - v_reg);
        hn_last = fmaxf(v_reg, 0.f);
        __hip_atomic_store(hxu + (size_t)t * 4096 + b * 512 + i,
                           __float_as_uint(hn_last),
                           __ATOMIC_RELAXED, __HIP_MEMORY_SCOPE_AGENT);
      }
      __builtin_amdgcn_s_waitcnt(0);  // drain h store before announcing
      __syncthreads();
      if (tid == 0)
        __hip_atomic_store(flg + (t * 8 + b) * 32 + q, 1u,
                           __ATOMIC_RELAXED, __HIP_MEMORY_SCOPE_AGENT);
    }
  }

  // ---- final writes ----
#pragma unroll
  for (int m = 0; m < 8; m++) {
    int c = m * 64 + L;
    float alv = al[m];
    o_dU[row + c] = (alv != 0.f) ? D[m] * __builtin_amdgcn_rcpf(alv) : 0.f;
    o_tE[row + c] = tE[m];
  }
  if (L == 0) {
    o_v[b * 512 + i] = v_reg;
    o_h[b * 512 + i] = hn_last;
  }
  if (q == 0 && tid < 512) o_te[b * 512 + tid] = sh_te[tid];
}

extern "C" void kernel_launch(void* const* d_in, const int* in_sizes, int n_in,
                              void* d_out, int out_size, void* d_ws, size_t ws_size,
                              hipStream_t stream) {
  const float* x       = (const float*)d_in[0];
  const float* h0      = (const float*)d_in[1];
  const float* v0      = (const float*)d_in[2];
  const float* dU0     = (const float*)d_in[3];
  const float* te0     = (const float*)d_in[4];
  const float* tE0     = (const float*)d_in[5];
  const float* x2h_v   = (const float*)d_in[6];
  const float* x2h_g   = (const float*)d_in[7];
  const float* x2h_b   = (const float*)d_in[8];
  const float* h2h_v   = (const float*)d_in[9];
  const float* h2h_g   = (const float*)d_in[10];
  const float* h2h_b   = (const float*)d_in[11];
  const float* alpha   = (const float*)d_in[12];
  const float* h2mod_w = (const float*)d_in[13];
  const float* h2mod_b = (const float*)d_in[14];
  const float* modU_w  = (const float*)d_in[15];
  const float* modU_b  = (const float*)d_in[16];

  float* out = (float*)d_out;
  // output layout: v(4096) h(4096) dU(2097152) te(4096) tE(2097152) outs(131072)
  float* o_v    = out;
  float* o_h    = out + 4096;
  float* o_dU   = out + 8192;
  float* o_te   = out + 2105344;
  float* o_tE   = out + 2109440;
  float* o_outs = out + 4206592;

  unsigned* flg = (unsigned*)d_ws;           // 32*8*32 arrival flags (32 KB)
  float* wsf = (float*)d_ws;
  float* scx = wsf + 8192;                   // 1536
  float* sch = wsf + 9728;                   // 1536

  prenorm_kernel<<<dim3(3072), dim3(64), 0, stream>>>(x2h_v, x2h_g, h2h_v, h2h_g,
                                                      scx, sch, flg);

  persist_kernel<<<dim3(256), dim3(1024), 0, stream>>>(
      x, h0, v0, dU0, te0, tE0, x2h_v, x2h_b, h2h_v, h2h_b, alpha,
      h2mod_w, h2mod_b, modU_w, modU_b, scx, sch, flg,
      o_v, o_h, o_dU, o_te, o_tE, o_outs);
}